// Round 2
// baseline (1125.615 us; speedup 1.0000x reference)
//
#include <hip/hip_runtime.h>
#include <math.h>

#define NN 50000
#define EE 800000
#define OO 4
#define CC 64
#define KDD 16
#define KEYDD 128

__device__ __forceinline__ float wave_sum64(float v) {
  for (int off = 32; off > 0; off >>= 1) v += __shfl_xor(v, off, 64);
  return v;
}
__device__ __forceinline__ float wave_max64(float v) {
  for (int off = 32; off > 0; off >>= 1) v = fmaxf(v, __shfl_xor(v, off, 64));
  return v;
}

// K0: tiny precompute. Gt[c2*64+c1] = sum_k keyW[k,c1]*qryW[k,c2];
// aVec[c] = sum_k keyB[k]*qryW[k,c]; bVec[c] = sum_k qryB[k]*keyW[k,c];
// c0 = keyB.qryB; fk[p,o,c] = dot16(fkb[p,o,:], fkw[c,:])
__global__ void prep_kernel(const float* __restrict__ keyW, const float* __restrict__ keyB,
                            const float* __restrict__ qryW, const float* __restrict__ qryB,
                            const float* __restrict__ fkb, const float* __restrict__ fkw,
                            float* __restrict__ Gt, float* __restrict__ aVec,
                            float* __restrict__ bVec, float* __restrict__ c0,
                            float* __restrict__ fk) {
  int t = threadIdx.x;
  for (int idx = t; idx < CC * CC; idx += 256) {
    int c2 = idx >> 6, c1 = idx & 63;
    float s = 0.f;
    for (int k = 0; k < KEYDD; ++k) s = fmaf(keyW[k * CC + c1], qryW[k * CC + c2], s);
    Gt[idx] = s;
  }
  if (t < CC) {
    float sa = 0.f, sb = 0.f;
    for (int k = 0; k < KEYDD; ++k) {
      sa = fmaf(keyB[k], qryW[k * CC + t], sa);
      sb = fmaf(qryB[k], keyW[k * CC + t], sb);
    }
    aVec[t] = sa; bVec[t] = sb;
  }
  if (t == 0) {
    float s = 0.f;
    for (int k = 0; k < KEYDD; ++k) s = fmaf(keyB[k], qryB[k], s);
    c0[0] = s;
  }
  for (int idx = t; idx < OO * OO * CC; idx += 256) {
    int p = idx >> 8, rem = idx & 255;
    int o = rem >> 6, c = rem & 63;
    float s = 0.f;
    for (int kd = 0; kd < KDD; ++kd)
      s = fmaf(fkb[(p * OO + o) * KDD + kd], fkw[c * KDD + kd], s);
    fk[idx] = s;
  }
}

// K1: u[row,:] = G x[row,:]; sA[row] = aVec.x[row]; sB[row] = bVec.x[row]
// 8 nodes per block (amortize the 16KB Gt LDS load); wave = one row.
// gtT is transposed + padded to 68 floats/row -> conflict-free ds_read_b128.
#define NPB 8
__global__ void node_proj_kernel(const float* __restrict__ x, const float* __restrict__ Gt,
                                 const float* __restrict__ aVec, const float* __restrict__ bVec,
                                 float* __restrict__ u, float* __restrict__ sA,
                                 float* __restrict__ sB) {
  __shared__ float gtT[CC * 68];
  __shared__ float xs[4 * CC];
  int t = threadIdx.x;
  for (int i = t; i < CC * CC; i += 256) {
    int c2 = i >> 6, c1 = i & 63;
    gtT[c1 * 68 + c2] = Gt[i];
  }
  int r = t >> 6, c = t & 63;
  float av = aVec[c], bv = bVec[c];
  for (int nn = 0; nn < NPB; ++nn) {
    int row = (blockIdx.x * NPB + nn) * 4 + r;
    __syncthreads();
    xs[t] = x[row * CC + c];
    __syncthreads();
    const float4* xr4 = reinterpret_cast<const float4*>(&xs[r * CC]);
    const float4* grow = reinterpret_cast<const float4*>(&gtT[c * 68]);
    float acc = 0.f;
    #pragma unroll
    for (int q = 0; q < 16; ++q) {
      float4 g = grow[q];
      float4 xv4 = xr4[q];
      acc = fmaf(g.x, xv4.x, acc);
      acc = fmaf(g.y, xv4.y, acc);
      acc = fmaf(g.z, xv4.z, acc);
      acc = fmaf(g.w, xv4.w, acc);
    }
    u[row * CC + c] = acc;
    float xv = xs[r * CC + c];
    float pa = wave_sum64(av * xv);
    float pb = wave_sum64(bv * xv);
    if (c == 0) { sA[row] = pa; sB[row] = pb; }
  }
}

// K2: logits[e,o] = (x[src,o,:].u[dst,o,:] + sB[src,o] + sA[dst,o] + c0)/sqrt(128)
// One wave per edge; lane layout o=lane>>4, c4=lane&15; float4 loads cover the
// whole 1KB fiber; 4-step 16-lane reduce. 8 edges/wave, ei prefetched.
__global__ void logits_kernel(const float* __restrict__ x, const float* __restrict__ u,
                              const float* __restrict__ sA, const float* __restrict__ sB,
                              const float* __restrict__ c0p, const int* __restrict__ ei,
                              float* __restrict__ logits, float* __restrict__ partials) {
  int t = threadIdx.x;
  int wave = t >> 6, lane = t & 63;
  int o = lane >> 4;
  const float scale = 0.08838834764831845f;  // 1/sqrt(128)
  float c0 = c0p[0];
  float lmax = -3.4e38f;
  int ebase = blockIdx.x * 32 + wave * 8;
  int sN = ei[ebase], dN = ei[EE + ebase];
  for (int j = 0; j < 8; ++j) {
    int e = ebase + j;
    int s = sN, d = dN;
    if (j < 7) { sN = ei[e + 1]; dN = ei[EE + e + 1]; }
    float4 xv = reinterpret_cast<const float4*>(x + (size_t)s * (OO * CC))[lane];
    float4 uv = reinterpret_cast<const float4*>(u + (size_t)d * (OO * CC))[lane];
    float p = xv.x * uv.x + xv.y * uv.y + xv.z * uv.z + xv.w * uv.w;
    p += __shfl_xor(p, 1, 64);
    p += __shfl_xor(p, 2, 64);
    p += __shfl_xor(p, 4, 64);
    p += __shfl_xor(p, 8, 64);
    float l = (p + sB[s * OO + o] + sA[d * OO + o] + c0) * scale;
    lmax = fmaxf(lmax, l);
    if ((lane & 15) == 0) logits[e * OO + o] = l;
  }
  lmax = wave_max64(lmax);
  __shared__ float wmax[4];
  if (lane == 0) wmax[wave] = lmax;
  __syncthreads();
  if (t == 0)
    partials[blockIdx.x] = fmaxf(fmaxf(wmax[0], wmax[1]), fmaxf(wmax[2], wmax[3]));
}

// K3: reduce 25000 partial maxima -> gmax[0]
__global__ void max_reduce_kernel(const float* __restrict__ partials, int n,
                                  float* __restrict__ gmax) {
  __shared__ float wred[16];
  int t = threadIdx.x;
  float m = -3.4e38f;
  for (int i = t; i < n; i += 1024) m = fmaxf(m, partials[i]);
  m = wave_max64(m);
  if ((t & 63) == 0) wred[t >> 6] = m;
  __syncthreads();
  if (t == 0) {
    float mm = -3.4e38f;
    for (int w = 0; w < 16; ++w) mm = fmaxf(mm, wred[w]);
    gmax[0] = mm;
  }
}

// K4: expv = exp(logit - gmax) (in place); denom[dst,o] += expv
__global__ void exp_denom_kernel(float* __restrict__ logits, const int* __restrict__ ei,
                                 const float* __restrict__ gmax, float* __restrict__ denom) {
  int i = blockIdx.x * 256 + threadIdx.x;  // covers E*O exactly
  float g = gmax[0];
  float v = expf(logits[i] - g);
  logits[i] = v;
  int e = i >> 2, o = i & 3;
  int d = ei[EE + e];
  atomicAdd(&denom[d * OO + o], v);
}

// K5a: CSR degree counts
__global__ void count_kernel(const int* __restrict__ ei, int* __restrict__ counts) {
  int e = blockIdx.x * 256 + threadIdx.x;
  if (e < EE) atomicAdd(&counts[ei[EE + e]], 1);
}

// K5b: single-block chunked exclusive scan: thread-local 49-elem chunks,
// one 1024-wide Hillis-Steele over chunk sums (20 barriers total, not 490).
__global__ void scan_kernel(const int* __restrict__ counts, int* __restrict__ offsets, int n) {
  __shared__ int sums[1024];
  int t = threadIdx.x;
  int chunk = (n + 1023) >> 10;
  int begin = t * chunk;
  int finish = min(begin + chunk, n);
  int s = 0;
  for (int i = begin; i < finish; ++i) s += counts[i];
  sums[t] = s;
  __syncthreads();
  for (int off = 1; off < 1024; off <<= 1) {
    int v = sums[t];
    int w = (t >= off) ? sums[t - off] : 0;
    __syncthreads();
    sums[t] = v + w;
    __syncthreads();
  }
  int excl = (t == 0) ? 0 : sums[t - 1];
  for (int i = begin; i < finish; ++i) {
    offsets[i] = excl;
    excl += counts[i];
  }
  if (t == 1023) offsets[n] = excl;
}

// K5c: fill CSR edge list
__global__ void fill_kernel(const int* __restrict__ ei, const int* __restrict__ offsets,
                            int* __restrict__ cursor, int* __restrict__ edge_list) {
  int e = blockIdx.x * 256 + threadIdx.x;
  if (e < EE) {
    int d = ei[EE + e];
    int pos = offsets[d] + atomicAdd(&cursor[d], 1);
    edge_list[pos] = e;
  }
}

// K6: per-node gather-aggregate + fiber mixing + bias. block = node, thread = (o,c).
// No in-loop barriers: kb read as wave-uniform float4s, indices pipelined 2 deep.
__global__ void aggregate_kernel(const float* __restrict__ x, const float* __restrict__ kb,
                                 const float* __restrict__ kW, const float* __restrict__ expv,
                                 const float* __restrict__ denom, const int* __restrict__ ei,
                                 const int* __restrict__ offsets,
                                 const int* __restrict__ edge_list,
                                 const float* __restrict__ fkg, const float* __restrict__ bias,
                                 float* __restrict__ out) {
  __shared__ float fk[OO * OO * CC];
  __shared__ float x1[OO * CC];
  int n = blockIdx.x;
  int t = threadIdx.x;
  int o = t >> 6, c = t & 63;
  for (int i = t; i < OO * OO * CC; i += 256) fk[i] = fkg[i];
  float4 kw0 = reinterpret_cast<const float4*>(kW + c * KDD)[0];
  float4 kw1 = reinterpret_cast<const float4*>(kW + c * KDD)[1];
  float4 kw2 = reinterpret_cast<const float4*>(kW + c * KDD)[2];
  float4 kw3 = reinterpret_cast<const float4*>(kW + c * KDD)[3];
  float invd = 1.0f / (denom[n * OO + o] + 1e-6f);
  int start = offsets[n], end = offsets[n + 1];
  float acc = 0.f;
  int e0 = 0, s0 = 0, e1 = 0, s1 = 0;
  if (start < end)     { e0 = edge_list[start];     s0 = ei[e0]; }
  if (start + 1 < end) { e1 = edge_list[start + 1]; s1 = ei[e1]; }
  for (int j = start; j < end; ++j) {
    int e2 = 0, s2i = 0;
    if (j + 2 < end) { e2 = edge_list[j + 2]; s2i = ei[e2]; }
    const float4* kbp = reinterpret_cast<const float4*>(kb + (size_t)e0 * (OO * KDD) + o * KDD);
    float4 b0 = kbp[0], b1 = kbp[1], b2 = kbp[2], b3 = kbp[3];
    float att = expv[e0 * OO + o] * invd;
    float k = 0.f;
    k = fmaf(b0.x, kw0.x, k); k = fmaf(b0.y, kw0.y, k);
    k = fmaf(b0.z, kw0.z, k); k = fmaf(b0.w, kw0.w, k);
    k = fmaf(b1.x, kw1.x, k); k = fmaf(b1.y, kw1.y, k);
    k = fmaf(b1.z, kw1.z, k); k = fmaf(b1.w, kw1.w, k);
    k = fmaf(b2.x, kw2.x, k); k = fmaf(b2.y, kw2.y, k);
    k = fmaf(b2.z, kw2.z, k); k = fmaf(b2.w, kw2.w, k);
    k = fmaf(b3.x, kw3.x, k); k = fmaf(b3.y, kw3.y, k);
    k = fmaf(b3.z, kw3.z, k); k = fmaf(b3.w, kw3.w, k);
    float xv = x[(size_t)s0 * (OO * CC) + t];
    acc = fmaf(xv, k * att, acc);
    e0 = e1; s0 = s1;
    e1 = e2; s1 = s2i;
  }
  __syncthreads();
  x1[t] = acc;  // x1[o*64 + c]
  __syncthreads();
  float s2 = 0.f;
  #pragma unroll
  for (int oo = 0; oo < OO; ++oo)
    s2 = fmaf(x1[oo * CC + c], fk[o * (OO * CC) + oo * CC + c], s2);
  out[n * (OO * CC) + t] = 0.25f * s2 + bias[c];
}

extern "C" void kernel_launch(void* const* d_in, const int* in_sizes, int n_in,
                              void* d_out, int out_size, void* d_ws, size_t ws_size,
                              hipStream_t stream) {
  const float* x    = (const float*)d_in[0];
  const float* kb   = (const float*)d_in[1];
  const float* fkb  = (const float*)d_in[2];
  const int*   ei   = (const int*)d_in[3];
  const float* kW   = (const float*)d_in[4];
  const float* fkW  = (const float*)d_in[5];
  const float* keyW = (const float*)d_in[6];
  const float* keyB = (const float*)d_in[7];
  const float* qryW = (const float*)d_in[8];
  const float* qryB = (const float*)d_in[9];
  const float* bias = (const float*)d_in[10];
  float* out = (float*)d_out;

  float* wsf   = (float*)d_ws;
  float* Gt    = wsf;                       // 4096
  float* aVec  = Gt + 4096;                 // 64
  float* bVec  = aVec + 64;                 // 64
  float* c0    = bVec + 64;                 // 1 (+pad)
  float* gmax  = c0 + 1;                    // 1
  float* fk    = c0 + 64;                   // 1024
  float* u     = fk + 1024;                 // 12.8M
  float* sA    = u + (size_t)NN * OO * CC;  // 200000
  float* sB    = sA + NN * OO;              // 200000
  float* logits = sB + NN * OO;             // 3.2M (doubles as expv)
  float* denom = logits + (size_t)EE * OO;  // 200000
  float* partials = denom + NN * OO;        // 25000
  int* counts    = (int*)(partials + 25000);
  int* cursor    = counts + NN;
  int* offsets   = cursor + NN;
  int* edge_list = offsets + NN + 1;

  hipMemsetAsync(denom, 0, (size_t)NN * OO * sizeof(float), stream);
  hipMemsetAsync(counts, 0, (size_t)NN * sizeof(int), stream);
  hipMemsetAsync(cursor, 0, (size_t)NN * sizeof(int), stream);

  prep_kernel<<<1, 256, 0, stream>>>(keyW, keyB, qryW, qryB, fkb, fkW, Gt, aVec, bVec, c0, fk);
  count_kernel<<<(EE + 255) / 256, 256, 0, stream>>>(ei, counts);
  scan_kernel<<<1, 1024, 0, stream>>>(counts, offsets, NN);
  fill_kernel<<<(EE + 255) / 256, 256, 0, stream>>>(ei, offsets, cursor, edge_list);
  node_proj_kernel<<<NN / NPB, 256, 0, stream>>>(x, Gt, aVec, bVec, u, sA, sB);
  logits_kernel<<<EE / 32, 256, 0, stream>>>(x, u, sA, sB, c0, ei, logits, partials);
  max_reduce_kernel<<<1, 1024, 0, stream>>>(partials, EE / 32, gmax);
  exp_denom_kernel<<<EE * OO / 256, 256, 0, stream>>>(logits, ei, gmax, denom);
  aggregate_kernel<<<NN, 256, 0, stream>>>(x, kb, kW, logits, denom, ei, offsets, edge_list,
                                           fk, bias, out);
}

// Round 3
// 979.073 us; speedup vs baseline: 1.1497x; 1.1497x over previous
//
#include <hip/hip_runtime.h>
#include <math.h>

#define NN 50000
#define EE 800000
#define OO 4
#define CC 64
#define KDD 16
#define KEYDD 128
#define ECAP 256  // LDS edge-staging capacity per node (max degree ~50 at Poisson(16))

__device__ __forceinline__ float wave_sum64(float v) {
  for (int off = 32; off > 0; off >>= 1) v += __shfl_xor(v, off, 64);
  return v;
}

// K0: precompute. Mrow[c1*64+c2] = sum_k keyW[k,c1]*qryW[k,c2]  (row-major in c1)
// aVec[c] = sum_k keyB[k]*qryW[k,c]; bVec[c] = sum_k qryB[k]*keyW[k,c];
// c0 = keyB.qryB; fk[p,o,c] = dot16(fkb[p,o,:], fkw[c,:])
__global__ void prep_kernel(const float* __restrict__ keyW, const float* __restrict__ keyB,
                            const float* __restrict__ qryW, const float* __restrict__ qryB,
                            const float* __restrict__ fkb, const float* __restrict__ fkw,
                            float* __restrict__ Mrow, float* __restrict__ aVec,
                            float* __restrict__ bVec, float* __restrict__ c0,
                            float* __restrict__ fk) {
  int t = threadIdx.x;
  for (int idx = t; idx < CC * CC; idx += 256) {
    int c1 = idx >> 6, c2 = idx & 63;
    float s = 0.f;
    for (int k = 0; k < KEYDD; ++k) s = fmaf(keyW[k * CC + c1], qryW[k * CC + c2], s);
    Mrow[idx] = s;  // M[c1][c2]
  }
  if (t < CC) {
    float sa = 0.f, sb = 0.f;
    for (int k = 0; k < KEYDD; ++k) {
      sa = fmaf(keyB[k], qryW[k * CC + t], sa);
      sb = fmaf(qryB[k], keyW[k * CC + t], sb);
    }
    aVec[t] = sa; bVec[t] = sb;
  }
  if (t == 0) {
    float s = 0.f;
    for (int k = 0; k < KEYDD; ++k) s = fmaf(keyB[k], qryB[k], s);
    c0[0] = s;
  }
  for (int idx = t; idx < OO * OO * CC; idx += 256) {
    int p = idx >> 8, rem = idx & 255;
    int o = rem >> 6, c = rem & 63;
    float s = 0.f;
    for (int kd = 0; kd < KDD; ++kd)
      s = fmaf(fkb[(p * OO + o) * KDD + kd], fkw[c * KDD + kd], s);
    fk[idx] = s;
  }
}

// K1: ub[row,c] = sum_c2 M[c,c2]*x[row,c2] + bVec[c];  sA[row] = aVec . x[row,:]
// block = 4 rows (1 node), wave = 1 row. M (16KB) read from global, L1-resident.
__global__ void node_proj_kernel(const float* __restrict__ x, const float* __restrict__ Mrow,
                                 const float* __restrict__ aVec, const float* __restrict__ bVec,
                                 float* __restrict__ ub_g, float* __restrict__ sAt) {
  __shared__ float xs[4 * CC];
  int t = threadIdx.x, r = t >> 6, c = t & 63;
  size_t row = (size_t)blockIdx.x * 4 + r;
  float xv = x[row * CC + c];
  xs[t] = xv;
  __syncthreads();
  const float4* m4 = reinterpret_cast<const float4*>(Mrow + c * CC);
  const float4* xs4 = reinterpret_cast<const float4*>(&xs[r * CC]);
  float accv = 0.f;
  #pragma unroll
  for (int q = 0; q < 16; ++q) {
    float4 mm = m4[q];
    float4 xx = xs4[q];
    accv = fmaf(mm.x, xx.x, accv);
    accv = fmaf(mm.y, xx.y, accv);
    accv = fmaf(mm.z, xx.z, accv);
    accv = fmaf(mm.w, xx.w, accv);
  }
  ub_g[row * CC + c] = accv + bVec[c];
  float pa = wave_sum64(aVec[c] * xv);
  if (c == 0) sAt[row] = pa;
}

// K2a: CSR degree counts
__global__ void count_kernel(const int* __restrict__ ei, int* __restrict__ counts) {
  int e = blockIdx.x * 256 + threadIdx.x;
  if (e < EE) atomicAdd(&counts[ei[EE + e]], 1);
}

// K2b: single-block chunked exclusive scan
__global__ void scan_kernel(const int* __restrict__ counts, int* __restrict__ offsets, int n) {
  __shared__ int sums[1024];
  int t = threadIdx.x;
  int chunk = (n + 1023) >> 10;
  int begin = t * chunk;
  int finish = min(begin + chunk, n);
  int s = 0;
  for (int i = begin; i < finish; ++i) s += counts[i];
  sums[t] = s;
  __syncthreads();
  for (int off = 1; off < 1024; off <<= 1) {
    int v = sums[t];
    int w = (t >= off) ? sums[t - off] : 0;
    __syncthreads();
    sums[t] = v + w;
    __syncthreads();
  }
  int excl = (t == 0) ? 0 : sums[t - 1];
  for (int i = begin; i < finish; ++i) {
    offsets[i] = excl;
    excl += counts[i];
  }
  if (t == 1023) offsets[n] = excl;
}

// K2c: fill CSR edge list
__global__ void fill_kernel(const int* __restrict__ ei, const int* __restrict__ offsets,
                            int* __restrict__ cursor, int* __restrict__ edge_list) {
  int e = blockIdx.x * 256 + threadIdx.x;
  if (e < EE) {
    int d = ei[EE + e];
    int pos = offsets[d] + atomicAdd(&cursor[d], 1);
    edge_list[pos] = e;
  }
}

// K3: MEGA — per node: logits + online softmax + attention aggregation + fiber mix.
// block = node (256 thr), wave = o, lane = c.
// logit(e,o) = (x[s,o,:].ub[d,o,:] + sA[d,o] + c0) * scale   (ub = u + bVec folds sB)
// online: m,S running per (wave); acc = sum exp(l-m)*k*xv; att = exp/(S+1e-6).
__global__ void mega_kernel(const float* __restrict__ x, const float* __restrict__ ub_g,
                            const float* __restrict__ sAt, const float* __restrict__ c0p,
                            const float* __restrict__ kb, const float* __restrict__ kW,
                            const int* __restrict__ ei, const int* __restrict__ offsets,
                            const int* __restrict__ edge_list,
                            const float* __restrict__ fkg, const float* __restrict__ bias,
                            float* __restrict__ out) {
  __shared__ int eidL[ECAP];
  __shared__ int srcL[ECAP];
  __shared__ float x1[OO * CC];
  int n = blockIdx.x;
  int t = threadIdx.x;
  int o = t >> 6, c = t & 63;
  const float scale = 0.08838834764831845f;  // 1/sqrt(128)

  int js = offsets[n], je = offsets[n + 1];
  int deg = je - js;
  // stage edge ids + src ids (one parallel round; deg <= ECAP in practice)
  int bound = min(deg, ECAP);
  for (int idx = t; idx < bound; idx += 256) {
    int e = edge_list[js + idx];
    eidL[idx] = e;
    srcL[idx] = ei[e];
  }
  // per-thread constants
  float ubr = ub_g[(size_t)n * (OO * CC) + t];
  float base_o = (sAt[n * OO + o] + c0p[0]) * scale;
  const float4* kw4 = reinterpret_cast<const float4*>(kW + c * KDD);
  float4 kw0 = kw4[0], kw1 = kw4[1], kw2 = kw4[2], kw3 = kw4[3];
  __syncthreads();

  float m = -INFINITY, S = 0.f, acc = 0.f;
  float xv = 0.f, kv = 0.f;
  if (deg > 0) {  // prologue: values for edge 0
    int eo = __builtin_amdgcn_readfirstlane(eidL[0] * OO + o);
    int so = __builtin_amdgcn_readfirstlane(srcL[0] * OO + o);
    xv = x[(size_t)so * CC + c];
    const float4* p = reinterpret_cast<const float4*>(kb + (size_t)eo * KDD);
    float4 b0 = p[0], b1 = p[1], b2 = p[2], b3 = p[3];
    kv = 0.f;
    kv = fmaf(b0.x, kw0.x, kv); kv = fmaf(b0.y, kw0.y, kv);
    kv = fmaf(b0.z, kw0.z, kv); kv = fmaf(b0.w, kw0.w, kv);
    kv = fmaf(b1.x, kw1.x, kv); kv = fmaf(b1.y, kw1.y, kv);
    kv = fmaf(b1.z, kw1.z, kv); kv = fmaf(b1.w, kw1.w, kv);
    kv = fmaf(b2.x, kw2.x, kv); kv = fmaf(b2.y, kw2.y, kv);
    kv = fmaf(b2.z, kw2.z, kv); kv = fmaf(b2.w, kw2.w, kv);
    kv = fmaf(b3.x, kw3.x, kv); kv = fmaf(b3.y, kw3.y, kv);
    kv = fmaf(b3.z, kw3.z, kv); kv = fmaf(b3.w, kw3.w, kv);
  }
  for (int j = 0; j < deg; ++j) {
    float xvc = xv, kvc = kv;
    float4 b0, b1, b2, b3;
    bool more = (j + 1 < deg);
    if (more) {  // issue loads for j+1 (hidden under this iteration's compute)
      int jn = j + 1;
      int e1, s1;
      if (jn < ECAP) { e1 = eidL[jn]; s1 = srcL[jn]; }
      else           { e1 = edge_list[js + jn]; s1 = ei[e1]; }  // overflow fallback
      int eo = __builtin_amdgcn_readfirstlane(e1 * OO + o);
      int so = __builtin_amdgcn_readfirstlane(s1 * OO + o);
      xv = x[(size_t)so * CC + c];
      const float4* p = reinterpret_cast<const float4*>(kb + (size_t)eo * KDD);
      b0 = p[0]; b1 = p[1]; b2 = p[2]; b3 = p[3];
    }
    // logit for edge j (wave-uniform after reduce)
    float dp = wave_sum64(xvc * ubr);
    float l = fmaf(dp, scale, base_o);
    // online softmax update (branch is wave-uniform)
    float ev;
    if (l > m) {
      float r = __expf(m - l);   // first edge: exp(-inf)=0 -> S=1, acc=0
      S = fmaf(S, r, 1.0f);
      acc *= r;
      m = l;
      ev = 1.0f;
    } else {
      ev = __expf(l - m);
      S += ev;
    }
    acc = fmaf(ev * kvc, xvc, acc);
    if (more) {  // finish prefetch: kv for j+1
      float k2 = 0.f;
      k2 = fmaf(b0.x, kw0.x, k2); k2 = fmaf(b0.y, kw0.y, k2);
      k2 = fmaf(b0.z, kw0.z, k2); k2 = fmaf(b0.w, kw0.w, k2);
      k2 = fmaf(b1.x, kw1.x, k2); k2 = fmaf(b1.y, kw1.y, k2);
      k2 = fmaf(b1.z, kw1.z, k2); k2 = fmaf(b1.w, kw1.w, k2);
      k2 = fmaf(b2.x, kw2.x, k2); k2 = fmaf(b2.y, kw2.y, k2);
      k2 = fmaf(b2.z, kw2.z, k2); k2 = fmaf(b2.w, kw2.w, k2);
      k2 = fmaf(b3.x, kw3.x, k2); k2 = fmaf(b3.y, kw3.y, k2);
      k2 = fmaf(b3.z, kw3.z, k2); k2 = fmaf(b3.w, kw3.w, k2);
      kv = k2;
    }
  }
  float invd = 1.0f / (S + 1e-6f);
  x1[t] = acc * invd;
  __syncthreads();
  // fiber mix: out[n,p=o,c] = 0.25 * sum_oo x1[oo,c]*fk[o,oo,c] + bias[c]
  float s2s = 0.f;
  #pragma unroll
  for (int oo = 0; oo < OO; ++oo)
    s2s = fmaf(x1[oo * CC + c], fkg[o * (OO * CC) + oo * CC + c], s2s);
  out[(size_t)n * (OO * CC) + t] = 0.25f * s2s + bias[c];
}

extern "C" void kernel_launch(void* const* d_in, const int* in_sizes, int n_in,
                              void* d_out, int out_size, void* d_ws, size_t ws_size,
                              hipStream_t stream) {
  const float* x    = (const float*)d_in[0];
  const float* kb   = (const float*)d_in[1];
  const float* fkb  = (const float*)d_in[2];
  const int*   ei   = (const int*)d_in[3];
  const float* kW   = (const float*)d_in[4];
  const float* fkW  = (const float*)d_in[5];
  const float* keyW = (const float*)d_in[6];
  const float* keyB = (const float*)d_in[7];
  const float* qryW = (const float*)d_in[8];
  const float* qryB = (const float*)d_in[9];
  const float* bias = (const float*)d_in[10];
  float* out = (float*)d_out;

  float* wsf  = (float*)d_ws;
  float* Mrow = wsf;                        // 4096
  float* aVec = Mrow + 4096;                // 64
  float* bVec = aVec + 64;                  // 64
  float* c0   = bVec + 64;                  // 1 (+63 pad)
  float* fk   = c0 + 64;                    // 1024
  float* ub_g = fk + 1024;                  // 12.8M
  float* sAt  = ub_g + (size_t)NN * OO * CC;  // 200000
  int* counts    = (int*)(sAt + NN * OO);
  int* cursor    = counts + NN;
  int* offsets   = cursor + NN;
  int* edge_list = offsets + NN + 1;

  hipMemsetAsync(counts, 0, (size_t)NN * sizeof(int), stream);
  hipMemsetAsync(cursor, 0, (size_t)NN * sizeof(int), stream);

  prep_kernel<<<1, 256, 0, stream>>>(keyW, keyB, qryW, qryB, fkb, fkW, Mrow, aVec, bVec, c0, fk);
  count_kernel<<<(EE + 255) / 256, 256, 0, stream>>>(ei, counts);
  scan_kernel<<<1, 1024, 0, stream>>>(counts, offsets, NN);
  fill_kernel<<<(EE + 255) / 256, 256, 0, stream>>>(ei, offsets, cursor, edge_list);
  node_proj_kernel<<<NN, 256, 0, stream>>>(x, Mrow, aVec, bVec, ub_g, sAt);
  mega_kernel<<<NN, 256, 0, stream>>>(x, ub_g, sAt, c0, kb, kW, ei, offsets, edge_list,
                                      fk, bias, out);
}